// Round 3
// baseline (2810.352 us; speedup 1.0000x reference)
//
#include <hip/hip_runtime.h>
#include <hip/hip_bf16.h>

typedef short short8 __attribute__((ext_vector_type(8)));
typedef float f32x4 __attribute__((ext_vector_type(4)));

// ---- workspace layout (bytes) ----
#define OFF_U   0x0UL        // U bf16 [1024][1024]        2 MiB
#define OFF_W   0x200000UL   // W bf16 [1024][512]         1 MiB
#define OFF_PRE 0x300000UL   // pre bf16 [t=512][b=128][i=1024]  128 MiB
#define OFF_H0  0x8300000UL  // h buf0 bf16 [128][1024]    256 KiB
#define OFF_H1  0x8340000UL  // h buf1 bf16 [128][1024]    256 KiB
#define OFF_CNT 0x8380000UL  // flags uint[4 clusters][2 streams][32] (128B line each)

static __device__ __forceinline__ unsigned short f2bf(float f) {
  return __builtin_bit_cast(unsigned short, __float2bfloat16(f));
}
static __device__ __forceinline__ float bf2f(unsigned short u) {
  unsigned int v = (unsigned int)u << 16;
  return __builtin_bit_cast(float, v);
}
static __device__ __forceinline__ unsigned int pack2(float a, float b) {
  return (unsigned int)f2bf(a) | ((unsigned int)f2bf(b) << 16);
}
static __device__ __forceinline__ float fast_tanh(float x) {
  float xc = fminf(fmaxf(x, -10.f), 10.f);
  float e2 = __expf(2.f * xc);
  return 1.f - 2.f * __builtin_amdgcn_rcpf(e2 + 1.f);
}

// ---------------- fp32 -> bf16 bulk convert ----------------
__global__ __launch_bounds__(256) void cvt_bf16(const float* __restrict__ in,
                                                unsigned short* __restrict__ out, int n4) {
  int idx = blockIdx.x * 256 + threadIdx.x;
  if (idx < n4) {
    float4 v = *(const float4*)&in[idx * 4];
    uint2 p; p.x = pack2(v.x, v.y); p.y = pack2(v.z, v.w);
    *(uint2*)&out[idx * 4] = p;
  }
}

// ---------------- pre = gather(emb,x) @ W^T   (stored [t][b][i], bf16, NO bias) --------
__global__ __launch_bounds__(256) void pre_gemm(const int* __restrict__ x,
                                                const float* __restrict__ emb,
                                                const unsigned short* __restrict__ Wbf,
                                                unsigned short* __restrict__ pre) {
  const int t   = blockIdx.y;           // 0..511
  const int n0  = blockIdx.x * 128;     // i offset
  const int tid = threadIdx.x;
  const int lane = tid & 63, w = tid >> 6;
  const int q = lane >> 4, l15 = lane & 15;

  __shared__ unsigned short Alds[128][72];  // +8 pad
  __shared__ unsigned short Blds[128][72];
  __shared__ int tok[128];
  if (tid < 128) tok[tid] = x[tid * 512 + t];   // x[b][t]
  __syncthreads();

  f32x4 acc[4][4];
  #pragma unroll
  for (int a = 0; a < 4; ++a)
    #pragma unroll
    for (int b = 0; b < 4; ++b) acc[a][b] = {0.f, 0.f, 0.f, 0.f};

  const int wm = (w & 1) * 64, wn = (w >> 1) * 64;

  for (int k0 = 0; k0 < 512; k0 += 64) {
    #pragma unroll
    for (int it = 0; it < 8; ++it) {
      int idx = it * 256 + tid;
      int r = idx >> 4, c4 = (idx & 15) * 4;
      float4 v = *(const float4*)&emb[tok[r] * 512 + k0 + c4];
      uint2 p; p.x = pack2(v.x, v.y); p.y = pack2(v.z, v.w);
      *(uint2*)&Alds[r][c4] = p;
    }
    #pragma unroll
    for (int it = 0; it < 4; ++it) {
      int idx = it * 256 + tid;
      int r = idx >> 3, c8 = (idx & 7) * 8;
      *(int4*)&Blds[r][c8] = *(const int4*)&Wbf[(n0 + r) * 512 + k0 + c8];
    }
    __syncthreads();
    #pragma unroll
    for (int kt = 0; kt < 2; ++kt) {
      short8 af[4], bfr[4];
      #pragma unroll
      for (int mt = 0; mt < 4; ++mt) af[mt]  = *(const short8*)&Alds[wm + mt*16 + l15][kt*32 + q*8];
      #pragma unroll
      for (int nt = 0; nt < 4; ++nt) bfr[nt] = *(const short8*)&Blds[wn + nt*16 + l15][kt*32 + q*8];
      #pragma unroll
      for (int mt = 0; mt < 4; ++mt)
        #pragma unroll
        for (int nt = 0; nt < 4; ++nt)
          acc[mt][nt] = __builtin_amdgcn_mfma_f32_16x16x32_bf16(af[mt], bfr[nt], acc[mt][nt], 0, 0, 0);
    }
    __syncthreads();
  }
  #pragma unroll
  for (int mt = 0; mt < 4; ++mt) {
    int brow = wm + mt * 16 + q * 4;
    #pragma unroll
    for (int nt = 0; nt < 4; ++nt) {
      int i = n0 + wn + nt * 16 + l15;
      #pragma unroll
      for (int r = 0; r < 4; ++r)
        pre[(t * 128 + brow + r) * 1024 + i] = f2bf(acc[mt][nt][r]);
    }
  }
}

// ---- poll: spin on this cluster-stream's 8 flags until all >= tt (round-7/9 proven) ----
static __device__ __forceinline__ void poll_flags(const unsigned int* fp, unsigned int tt,
                                                  bool pact) {
  unsigned int va, vb;
  asm volatile("global_load_dword %0, %1, off sc1" : "=v"(va) : "v"(fp));
  for (;;) {
    asm volatile("global_load_dword %0, %1, off sc1\n\ts_waitcnt vmcnt(1)"
                 : "=v"(vb) : "v"(fp));
    unsigned int x = pact ? va : tt;
    if (__ballot(x < tt) == 0) break;       // va is complete (vmcnt(1) retired it)
    asm volatile("global_load_dword %0, %1, off sc1\n\ts_waitcnt vmcnt(1)"
                 : "=v"(va) : "v"(fp));
    x = pact ? vb : tt;
    if (__ballot(x < tt) == 0) break;
  }
  // UB fix: drain the dangling poll load NOW, while va/vb are still live; a
  // dangling load's dest reg can be reused by the allocator and clobbered later.
  asm volatile("s_waitcnt vmcnt(0)");
}

// ---- stage: load remote h slices ONCE, tag-validate, write LDS (round-9 proven) ----
static __device__ __forceinline__ void stage_remote(const unsigned short* hp, unsigned int et,
                                                    bool notown, int sb, int sk,
                                                    unsigned short hlds[16][1032]) {
  if (notown) {
    int4 d0, d1, d2, d3;
    for (;;) {
      int4 r0, r1, r2, r3;
      asm volatile(
        "global_load_dwordx4 %0, %4, off sc1\n\t"
        "global_load_dwordx4 %1, %5, off sc1\n\t"
        "global_load_dwordx4 %2, %6, off sc1\n\t"
        "global_load_dwordx4 %3, %7, off sc1\n\t"
        "s_waitcnt vmcnt(0)"
        : "=&v"(r0), "=&v"(r1), "=&v"(r2), "=&v"(r3)
        : "v"(hp), "v"(hp + 4 * 1024), "v"(hp + 8 * 1024), "v"(hp + 12 * 1024));
      // decode == check: XOR by expected tag; any bit14 left set => stale
      d0.x = r0.x ^ (int)et; d0.y = r0.y ^ (int)et; d0.z = r0.z ^ (int)et; d0.w = r0.w ^ (int)et;
      d1.x = r1.x ^ (int)et; d1.y = r1.y ^ (int)et; d1.z = r1.z ^ (int)et; d1.w = r1.w ^ (int)et;
      d2.x = r2.x ^ (int)et; d2.y = r2.y ^ (int)et; d2.z = r2.z ^ (int)et; d2.w = r2.w ^ (int)et;
      d3.x = r3.x ^ (int)et; d3.y = r3.y ^ (int)et; d3.z = r3.z ^ (int)et; d3.w = r3.w ^ (int)et;
      unsigned int bad = (unsigned int)(d0.x | d0.y | d0.z | d0.w |
                                        d1.x | d1.y | d1.z | d1.w |
                                        d2.x | d2.y | d2.z | d2.w |
                                        d3.x | d3.y | d3.z | d3.w) & 0x40004000u;
      if (bad == 0) break;
    }
    *(int4*)&hlds[sb][sk]      = d0;
    *(int4*)&hlds[sb + 4][sk]  = d1;
    *(int4*)&hlds[sb + 8][sk]  = d2;
    *(int4*)&hlds[sb + 12][sk] = d3;
  } else {
    asm volatile("s_waitcnt vmcnt(0)");   // drains pvr prefetches (+ dangling stores)
  }
}

// ---------------- persistent recurrence ----------------
// Round-10 = TWO-STREAM INTERLEAVE on top of round-9's flag+tag protocol.
// 32 wgs = 4 clusters (32 batches) x 8 i-slices. Each cluster runs TWO
// independent 16-batch recurrences (stream A = batches c*32..+15, stream B =
// c*32+16..+31), interleaved per step: P(A) S(A) C(A) P(B) S(B) C(B).
// While stream X's h stores + flag propagate through the fabric (~1 RT), the
// wg executes stream Y's stage+compute (~1500 cy) -> each poll finds its flags
// already set; only the stage-load RT + compute remain on the critical path.
//  * Own-slice short-circuit moved from LDS to REGISTERS (pk): epilogue keeps
//    the wave's own h values in regs; the NEXT stage phase writes them into
//    hlds. hlds is therefore dead between sub-steps -> one 33 KB buffer serves
//    both streams, and the post-MFMA barrier merges with the post-store one
//    (3 barriers per sub-step).
//  * Per-stream protocol byte-identical to round-9: bit14 phase tags
//    (tag(t)=((t>>1)&1)^1) on the global h copy, flag store races with data
//    (no producer drain), consumer loads data ONCE and tag-validates, poll
//    keeps the round-7 dangling-load UB fix.
//  * 2-buffer write-safety per stream unchanged: pollX(t) proves all cluster
//    wgs completed stream-X step t-1, hence finished reading h_{t-2}, before
//    buf[t&1] is overwritten. Streams touch disjoint batch rows + flag lines.
//  * t=511 stores tag 0 (raw) into h0 => final_out reads it untouched.
__global__ __launch_bounds__(512, 2) void recurrence(const unsigned short* __restrict__ Ubf,
                                                     const unsigned short* __restrict__ pre,
                                                     const float* __restrict__ Wb,
                                                     const float* __restrict__ Ub,
                                                     unsigned short* __restrict__ h0buf,
                                                     unsigned short* __restrict__ h1buf,
                                                     unsigned int* __restrict__ cnt) {
  const int c   = blockIdx.x & 3;        // cluster 0..3
  const int s   = blockIdx.x >> 2;       // i-slice 0..7
  const int tid = threadIdx.x;
  const int lane = tid & 63, wv = tid >> 6;
  const int q = lane >> 4, l15 = lane & 15;
  const int ibase = s * 128 + wv * 16;   // this wave's 16 i-rows
  const int bA = c * 32;                 // stream A batch base
  const int bB = c * 32 + 16;            // stream B batch base

  __shared__ unsigned short hlds[16][1032];   // [b][k], +8 pad; reused by both streams

  // U A-fragments: 32 k-tiles, pinned resident (128 regs); shared by both streams
  short8 A[32];
  {
    const unsigned short* Up = Ubf + (ibase + l15) * 1024 + q * 8;
    #pragma unroll
    for (int kt = 0; kt < 32; ++kt) A[kt] = *(const short8*)(Up + kt * 32);
  }
  #pragma unroll
  for (int kt = 0; kt < 32; ++kt) asm volatile("" : "+v"(A[kt]));  // forbid remat

  float4 bias;
  {
    int i0 = ibase + q * 4;
    float4 wb = *(const float4*)&Wb[i0];
    float4 ub = *(const float4*)&Ub[i0];
    bias = make_float4(wb.x + ub.x, wb.y + ub.y, wb.z + ub.z, wb.w + ub.w);
  }

  unsigned int* fbA = cnt + (c * 2 + 0) * 32;   // per cluster-stream 128B flag lines
  unsigned int* fbB = cnt + (c * 2 + 1) * 32;
  const bool pact = (lane < 8) && (lane != s);  // poll participation (skip own)
  const unsigned int* fpollA = fbA + (lane & 7);
  const unsigned int* fpollB = fbB + (lane & 7);
  unsigned int* fmineA = fbA + s;
  unsigned int* fmineB = fbB + s;
  const int sb = tid >> 7;              // staging row 0..3
  const int sk = (tid & 127) * 8;       // staging col (shorts)
  const bool notown = (sk >> 7) != s;   // this thread's 4 chunks are remote-slice
  const int i0 = ibase + q * 4;         // this thread's 4 own i-values
  const unsigned short* prebA = pre + (size_t)(bA + l15) * 1024 + i0;
  const unsigned short* prebB = pre + (size_t)(bB + l15) * 1024 + i0;

  // own-slice h values live in registers between steps; h_{-1} = 0
  uint2 pkA; pkA.x = 0u; pkA.y = 0u;
  uint2 pkB; pkB.x = 0u; pkB.y = 0u;

  #pragma unroll 1
  for (int t = 0; t < 512; ++t) {
    // pre prefetch for both streams — asm keeps our manual vmcnt FIFO authoritative
    uint2 pvrA, pvrB;
    {
      const unsigned short* pp = prebA + (size_t)t * 131072;
      asm volatile("global_load_dwordx2 %0, %1, off" : "=v"(pvrA) : "v"(pp));
    }
    {
      const unsigned short* pp = prebB + (size_t)t * 131072;
      asm volatile("global_load_dwordx2 %0, %1, off" : "=v"(pvrB) : "v"(pp));
    }

    const unsigned short* hprev = (t & 1) ? h1buf : h0buf;
    unsigned short* hnew        = (t & 1) ? h0buf : h1buf;
    // expected tag on h_{t-1} (t=0 reads memset zeros: tag 0, correct data)
    const unsigned int et = (t == 0) ? 0u
                          : (((((t - 1) >> 1) & 1) ^ 1) ? 0x40004000u : 0u);
    const unsigned int tm = (((t >> 1) & 1) ^ 1) ? 0x40004000u : 0u;  // tag(t)

    // ======================= sub-step A =======================
    if (t > 0) {
      if (wv == 0) poll_flags(fpollA, (unsigned int)t, pact);
      __syncthreads();   // broadcast poll success; also fences C(B,t-1) reads
    }
    {
      const unsigned short* hp = hprev + (size_t)(bA + sb) * 1024 + sk;
      stage_remote(hp, et, notown, sb, sk, hlds);
      *(uint2*)&hlds[l15][i0] = pkA;          // own slice from registers (raw)
    }
    __syncthreads();   // hlds(A) fully staged

    {
      f32x4 acc0 = {0.f, 0.f, 0.f, 0.f}, acc1 = {0.f, 0.f, 0.f, 0.f};
      #pragma unroll
      for (int kt = 0; kt < 32; kt += 2) {
        short8 b0 = *(const short8*)&hlds[l15][kt * 32 + q * 8];
        short8 b1 = *(const short8*)&hlds[l15][kt * 32 + 32 + q * 8];
        acc0 = __builtin_amdgcn_mfma_f32_16x16x32_bf16(A[kt],     b0, acc0, 0, 0, 0);
        acc1 = __builtin_amdgcn_mfma_f32_16x16x32_bf16(A[kt + 1], b1, acc1, 0, 0, 0);
      }
      // epilogue: D col=lane&15 -> batch, row=4q+r -> i
      float p0 = bf2f((unsigned short)(pvrA.x & 0xffff));
      float p1 = bf2f((unsigned short)(pvrA.x >> 16));
      float p2 = bf2f((unsigned short)(pvrA.y & 0xffff));
      float p3 = bf2f((unsigned short)(pvrA.y >> 16));
      float x0 = acc0[0] + acc1[0] + p0 + bias.x;
      float x1 = acc0[1] + acc1[1] + p1 + bias.y;
      float x2 = acc0[2] + acc1[2] + p2 + bias.z;
      float x3 = acc0[3] + acc1[3] + p3 + bias.w;
      pkA.x = pack2(fast_tanh(x0), fast_tanh(x1));
      pkA.y = pack2(fast_tanh(x2), fast_tanh(x3));
      uint2 pkt; pkt.x = pkA.x ^ tm; pkt.y = pkA.y ^ tm;
      unsigned short* dst = hnew + (size_t)(bA + l15) * 1024 + i0;
      asm volatile("global_store_dwordx2 %0, %1, off sc1"
                   : : "v"(dst), "v"(pkt));   // no drain: tags self-validate
    }
    __syncthreads();   // all waves done reading hlds(A) + issued h stores
    if (tid == 0) {
      unsigned int tv = (unsigned int)(t + 1);
      asm volatile("global_store_dword %0, %1, off sc1" : : "v"(fmineA), "v"(tv));
    }

    // ======================= sub-step B =======================
    if (t > 0) {
      if (wv == 0) poll_flags(fpollB, (unsigned int)t, pact);
      __syncthreads();
    }
    {
      const unsigned short* hp = hprev + (size_t)(bB + sb) * 1024 + sk;
      stage_remote(hp, et, notown, sb, sk, hlds);
      *(uint2*)&hlds[l15][i0] = pkB;
    }
    __syncthreads();   // hlds(B) fully staged

    {
      f32x4 acc0 = {0.f, 0.f, 0.f, 0.f}, acc1 = {0.f, 0.f, 0.f, 0.f};
      #pragma unroll
      for (int kt = 0; kt < 32; kt += 2) {
        short8 b0 = *(const short8*)&hlds[l15][kt * 32 + q * 8];
        short8 b1 = *(const short8*)&hlds[l15][kt * 32 + 32 + q * 8];
        acc0 = __builtin_amdgcn_mfma_f32_16x16x32_bf16(A[kt],     b0, acc0, 0, 0, 0);
        acc1 = __builtin_amdgcn_mfma_f32_16x16x32_bf16(A[kt + 1], b1, acc1, 0, 0, 0);
      }
      float p0 = bf2f((unsigned short)(pvrB.x & 0xffff));
      float p1 = bf2f((unsigned short)(pvrB.x >> 16));
      float p2 = bf2f((unsigned short)(pvrB.y & 0xffff));
      float p3 = bf2f((unsigned short)(pvrB.y >> 16));
      float x0 = acc0[0] + acc1[0] + p0 + bias.x;
      float x1 = acc0[1] + acc1[1] + p1 + bias.y;
      float x2 = acc0[2] + acc1[2] + p2 + bias.z;
      float x3 = acc0[3] + acc1[3] + p3 + bias.w;
      pkB.x = pack2(fast_tanh(x0), fast_tanh(x1));
      pkB.y = pack2(fast_tanh(x2), fast_tanh(x3));
      uint2 pkt; pkt.x = pkB.x ^ tm; pkt.y = pkB.y ^ tm;
      unsigned short* dst = hnew + (size_t)(bB + l15) * 1024 + i0;
      asm volatile("global_store_dwordx2 %0, %1, off sc1"
                   : : "v"(dst), "v"(pkt));
    }
    __syncthreads();
    if (tid == 0) {
      unsigned int tv = (unsigned int)(t + 1);
      asm volatile("global_store_dword %0, %1, off sc1" : : "v"(fmineB), "v"(tv));
    }
  }
}

// ---------------- final: sigmoid(h_T @ V^T + Vb) ----------------
__global__ __launch_bounds__(64) void final_out(const unsigned short* __restrict__ hT,
                                                const float* __restrict__ Vw,
                                                const float* __restrict__ Vb,
                                                float* __restrict__ out) {
  int b = blockIdx.x, lane = threadIdx.x;
  float sum = 0.f;
  #pragma unroll
  for (int k = 0; k < 16; ++k) {
    int i = k * 64 + lane;
    sum += bf2f(hT[b * 1024 + i]) * Vw[i];
  }
  #pragma unroll
  for (int off = 32; off; off >>= 1) sum += __shfl_down(sum, off);
  if (lane == 0) out[b] = 1.f / (1.f + expf(-(sum + Vb[0])));
}

extern "C" void kernel_launch(void* const* d_in, const int* in_sizes, int n_in,
                              void* d_out, int out_size, void* d_ws, size_t ws_size,
                              hipStream_t stream) {
  const int*   x   = (const int*)d_in[0];
  const float* emb = (const float*)d_in[1];
  const float* W_w = (const float*)d_in[2];
  const float* W_b = (const float*)d_in[3];
  const float* U_w = (const float*)d_in[4];
  const float* U_b = (const float*)d_in[5];
  const float* V_w = (const float*)d_in[6];
  const float* V_b = (const float*)d_in[7];
  float* out = (float*)d_out;
  char*  ws  = (char*)d_ws;

  unsigned short* Ubf = (unsigned short*)(ws + OFF_U);
  unsigned short* Wbf = (unsigned short*)(ws + OFF_W);
  unsigned short* pre = (unsigned short*)(ws + OFF_PRE);
  unsigned short* h0  = (unsigned short*)(ws + OFF_H0);
  unsigned short* h1  = (unsigned short*)(ws + OFF_H1);
  unsigned int*   cnt = (unsigned int*)(ws + OFF_CNT);

  // zero h0 (h_{-1}, tag 0 == valid zeros) + h1 + flags. Re-runs every replay.
  hipMemsetAsync(ws + OFF_H0, 0, (OFF_CNT - OFF_H0) + 0x1000, stream);

  cvt_bf16<<<1024, 256, 0, stream>>>(U_w, Ubf, 1024 * 1024 / 4);
  cvt_bf16<<<512, 256, 0, stream>>>(W_w, Wbf, 1024 * 512 / 4);

  pre_gemm<<<dim3(8, 512), 256, 0, stream>>>(x, emb, Wbf, pre);

  void* args[] = {&Ubf, &pre, &W_b, &U_b, &h0, &h1, &cnt};
  hipLaunchCooperativeKernel((void*)recurrence, dim3(32), dim3(512), args, 0, stream);

  // t=511 writes h0 with tag(511)=0 (raw bf16)
  final_out<<<128, 64, 0, stream>>>(h0, V_w, V_b, out);
}

// Round 6
// 1623.317 us; speedup vs baseline: 1.7312x; 1.7312x over previous
//
#include <hip/hip_runtime.h>
#include <hip/hip_bf16.h>

typedef short short8 __attribute__((ext_vector_type(8)));
typedef float f32x4 __attribute__((ext_vector_type(4)));
typedef int   i32x4 __attribute__((ext_vector_type(4)));   // asm-tie-safe 16B vector

// ---- workspace layout (bytes) ----
#define OFF_U   0x0UL        // U bf16 [1024][1024]        2 MiB
#define OFF_W   0x200000UL   // W bf16 [1024][512]         1 MiB
#define OFF_PRE 0x300000UL   // pre bf16 [t=512][b=128][i=1024]  128 MiB
#define OFF_H0  0x8300000UL  // h buf0 bf16 [128][1024]    256 KiB
#define OFF_H1  0x8340000UL  // h buf1 bf16 [128][1024]    256 KiB
#define OFF_CNT 0x8380000UL  // flags uint[8 clusters][32] (one 128B line per cluster)

static __device__ __forceinline__ unsigned short f2bf(float f) {
  return __builtin_bit_cast(unsigned short, __float2bfloat16(f));
}
static __device__ __forceinline__ float bf2f(unsigned short u) {
  unsigned int v = (unsigned int)u << 16;
  return __builtin_bit_cast(float, v);
}
static __device__ __forceinline__ unsigned int pack2(float a, float b) {
  return (unsigned int)f2bf(a) | ((unsigned int)f2bf(b) << 16);
}
static __device__ __forceinline__ float fast_tanh(float x) {
  float xc = fminf(fmaxf(x, -10.f), 10.f);
  float e2 = __expf(2.f * xc);
  return 1.f - 2.f * __builtin_amdgcn_rcpf(e2 + 1.f);
}

// ---------------- fp32 -> bf16 bulk convert ----------------
__global__ __launch_bounds__(256) void cvt_bf16(const float* __restrict__ in,
                                                unsigned short* __restrict__ out, int n4) {
  int idx = blockIdx.x * 256 + threadIdx.x;
  if (idx < n4) {
    float4 v = *(const float4*)&in[idx * 4];
    uint2 p; p.x = pack2(v.x, v.y); p.y = pack2(v.z, v.w);
    *(uint2*)&out[idx * 4] = p;
  }
}

// ---------------- pre = gather(emb,x) @ W^T   (stored [t][b][i], bf16, NO bias) --------
__global__ __launch_bounds__(256) void pre_gemm(const int* __restrict__ x,
                                                const float* __restrict__ emb,
                                                const unsigned short* __restrict__ Wbf,
                                                unsigned short* __restrict__ pre) {
  const int t   = blockIdx.y;           // 0..511
  const int n0  = blockIdx.x * 128;     // i offset
  const int tid = threadIdx.x;
  const int lane = tid & 63, w = tid >> 6;
  const int q = lane >> 4, l15 = lane & 15;

  __shared__ unsigned short Alds[128][72];  // +8 pad
  __shared__ unsigned short Blds[128][72];
  __shared__ int tok[128];
  if (tid < 128) tok[tid] = x[tid * 512 + t];   // x[b][t]
  __syncthreads();

  f32x4 acc[4][4];
  #pragma unroll
  for (int a = 0; a < 4; ++a)
    #pragma unroll
    for (int b = 0; b < 4; ++b) acc[a][b] = {0.f, 0.f, 0.f, 0.f};

  const int wm = (w & 1) * 64, wn = (w >> 1) * 64;

  for (int k0 = 0; k0 < 512; k0 += 64) {
    #pragma unroll
    for (int it = 0; it < 8; ++it) {
      int idx = it * 256 + tid;
      int r = idx >> 4, c4 = (idx & 15) * 4;
      float4 v = *(const float4*)&emb[tok[r] * 512 + k0 + c4];
      uint2 p; p.x = pack2(v.x, v.y); p.y = pack2(v.z, v.w);
      *(uint2*)&Alds[r][c4] = p;
    }
    #pragma unroll
    for (int it = 0; it < 4; ++it) {
      int idx = it * 256 + tid;
      int r = idx >> 3, c8 = (idx & 7) * 8;
      *(int4*)&Blds[r][c8] = *(const int4*)&Wbf[(n0 + r) * 512 + k0 + c8];
    }
    __syncthreads();
    #pragma unroll
    for (int kt = 0; kt < 2; ++kt) {
      short8 af[4], bfr[4];
      #pragma unroll
      for (int mt = 0; mt < 4; ++mt) af[mt]  = *(const short8*)&Alds[wm + mt*16 + l15][kt*32 + q*8];
      #pragma unroll
      for (int nt = 0; nt < 4; ++nt) bfr[nt] = *(const short8*)&Blds[wn + nt*16 + l15][kt*32 + q*8];
      #pragma unroll
      for (int mt = 0; mt < 4; ++mt)
        #pragma unroll
        for (int nt = 0; nt < 4; ++nt)
          acc[mt][nt] = __builtin_amdgcn_mfma_f32_16x16x32_bf16(af[mt], bfr[nt], acc[mt][nt], 0, 0, 0);
    }
    __syncthreads();
  }
  #pragma unroll
  for (int mt = 0; mt < 4; ++mt) {
    int brow = wm + mt * 16 + q * 4;
    #pragma unroll
    for (int nt = 0; nt < 4; ++nt) {
      int i = n0 + wn + nt * 16 + l15;
      #pragma unroll
      for (int r = 0; r < 4; ++r)
        pre[(t * 128 + brow + r) * 1024 + i] = f2bf(acc[mt][nt][r]);
    }
  }
}

// ---- poll: spin on this cluster's 8 flags until all >= tt (round-7/9 proven) ----
static __device__ __forceinline__ void poll_flags(const unsigned int* fp, unsigned int tt,
                                                  bool pact) {
  unsigned int va, vb;
  asm volatile("global_load_dword %0, %1, off sc1" : "=v"(va) : "v"(fp));
  for (;;) {
    asm volatile("global_load_dword %0, %1, off sc1\n\ts_waitcnt vmcnt(1)"
                 : "=v"(vb) : "v"(fp));
    unsigned int x = pact ? va : tt;
    if (__ballot(x < tt) == 0) break;       // va is complete (vmcnt(1) retired it)
    asm volatile("global_load_dword %0, %1, off sc1\n\ts_waitcnt vmcnt(1)"
                 : "=v"(va) : "v"(fp));
    x = pact ? vb : tt;
    if (__ballot(x < tt) == 0) break;
  }
  // UB fix: drain the dangling poll load NOW, while va/vb are still live; a
  // dangling load's dest reg can be reused by the allocator and clobbered later.
  asm volatile("s_waitcnt vmcnt(0)");
}

// ---------------- persistent recurrence ----------------
// Round-11c = round-11 with the REAL compile fix: "+v" register-tie pins work
// on clang ext_vector_type values (short8/A[kt] proven since round-7) but NOT
// on HIP struct vectors (int4) -- so the h-stage registers are i32x4
// (ext_vector_type) now. Semantics identical.
// Structure (see round-11 notes):
//  * 64 wgs, XCD-local clusters (cluster = bid&7): all 8 wgs of a cluster land
//    on one XCD under round-robin dispatch; h traffic stays in that XCD's L2.
//    Round-10 proved breaking this costs +62MB FETCH and 2x time.
//  1. TWO-DEEP pre pipeline: pre(t+2) issued inside stage(t) AFTER the h stage
//     loads; first-attempt stage wait is vmcnt(1) (leaves it in flight); it
//     retires a full step later -- HBM latency fully hidden. Roles P0/P1
//     alternate via 2x-unrolled body (no copies of in-flight load dests).
//     "+v" pins after waits stop decode-hoisting above the waitcnt (rule #18).
//     All global ops stay in asm so __syncthreads emits no vmcnt drain.
//  2. Post-MFMA barrier removed (4 -> 3 barriers/step): own-slice h lives in
//     regs (pk), written to hlds during the NEXT stage phase. Safe: reaching
//     the post-store barrier proves a wave's ds_reads retired (h-store
//     data-depends on MFMA accs which depend on the ds_reads).
// Protocol unchanged from round-9: per-cluster flags + bit14 phase tags
// (tag(t)=((t>>1)&1)^1), no producer drain, consumer loads data ONCE and
// tag-validates, poll keeps the dangling-load UB fix. t=511 stores tag 0
// (raw) into h0 => final_out reads it untouched.
__global__ __launch_bounds__(512, 2) void recurrence(const unsigned short* __restrict__ Ubf,
                                                     const unsigned short* __restrict__ pre,
                                                     const float* __restrict__ Wb,
                                                     const float* __restrict__ Ub,
                                                     unsigned short* __restrict__ h0buf,
                                                     unsigned short* __restrict__ h1buf,
                                                     unsigned int* __restrict__ cnt) {
  const int c   = blockIdx.x & 7;        // cluster == XCD (round-robin dispatch)
  const int s   = blockIdx.x >> 3;       // i-slice
  const int tid = threadIdx.x;
  const int lane = tid & 63, wv = tid >> 6;
  const int q = lane >> 4, l15 = lane & 15;
  const int ibase = s * 128 + wv * 16;   // this wave's 16 i-rows
  const int bglob = c * 16;

  __shared__ unsigned short hlds[16][1032];   // [b][k], +8 pad

  // U A-fragments: 32 k-tiles, pinned resident (128 regs)
  short8 A[32];
  {
    const unsigned short* Up = Ubf + (ibase + l15) * 1024 + q * 8;
    #pragma unroll
    for (int kt = 0; kt < 32; ++kt) A[kt] = *(const short8*)(Up + kt * 32);
  }
  #pragma unroll
  for (int kt = 0; kt < 32; ++kt) asm volatile("" : "+v"(A[kt]));  // forbid remat

  float4 bias;
  {
    int i0b = ibase + q * 4;
    float4 wb = *(const float4*)&Wb[i0b];
    float4 ub = *(const float4*)&Ub[i0b];
    bias = make_float4(wb.x + ub.x, wb.y + ub.y, wb.z + ub.z, wb.w + ub.w);
  }

  unsigned int* fbase = cnt + c * 32;             // this cluster's 128B flag line
  const bool pact = (lane < 8) && (lane != s);    // poll participation (skip own)
  const unsigned int* fpoll = fbase + (lane & 7);
  unsigned int* fmine = fbase + s;
  const int sb = tid >> 7;              // staging row 0..3
  const int sk = (tid & 127) * 8;       // staging col (shorts)
  const bool notown = (sk >> 7) != s;   // this thread's 4 chunks are remote-slice
  const int i0 = ibase + q * 4;         // this thread's 4 own i-values
  const unsigned short* prebase = pre + (size_t)(bglob + l15) * 1024 + i0;

  // own-slice h values live in regs between steps; h_{-1} = 0
  uint2 pk; pk.x = 0u; pk.y = 0u;

  // ---- pre pipeline prologue: pre(0) -> P0 (waited), pre(1) -> P1 (in flight)
  uint2 P0, P1;
  {
    const unsigned short* pp0 = prebase;
    const unsigned short* pp1 = prebase + 131072;
    asm volatile("global_load_dwordx2 %0, %1, off" : "=v"(P0) : "v"(pp0));
    asm volatile("global_load_dwordx2 %0, %1, off" : "=v"(P1) : "v"(pp1));
    asm volatile("s_waitcnt vmcnt(1)");   // P0 complete (retires any older too)
    asm volatile("" : "+v"(P0));          // order P0 reads after the wait
  }

  // body(t): Pcur holds pre(t) [complete+pinned]; Pnxt holds pre(t+1) [retired
  // by this body's vmcnt(1), pinned here for next body]. Issues pre(t+2) into
  // Pcur's register slot after extracting its value.
  auto body = [&](int t, uint2& Pcur, uint2& Pnxt) {
    const unsigned short* hprev = (t & 1) ? h1buf : h0buf;
    unsigned short* hnew        = (t & 1) ? h0buf : h1buf;
    const unsigned int et = (t == 0) ? 0u
                          : (((((t - 1) >> 1) & 1) ^ 1) ? 0x40004000u : 0u);
    const unsigned int tm = (((t >> 1) & 1) ^ 1) ? 0x40004000u : 0u;  // tag(t)

    if (t > 0) {
      if (wv == 0) poll_flags(fpoll, (unsigned int)t, pact);
      __syncthreads();   // broadcast poll success (barrier a)
    }

    // ---- stage phase: issue h loads, decode this step's pre, issue pre(t+2)
    const unsigned short* hp = hprev + (size_t)(bglob + sb) * 1024 + sk;
    i32x4 r0, r1, r2, r3;
    if (notown) {
      asm volatile(
        "global_load_dwordx4 %0, %4, off sc1\n\t"
        "global_load_dwordx4 %1, %5, off sc1\n\t"
        "global_load_dwordx4 %2, %6, off sc1\n\t"
        "global_load_dwordx4 %3, %7, off sc1"
        : "=&v"(r0), "=&v"(r1), "=&v"(r2), "=&v"(r3)
        : "v"(hp), "v"(hp + 4 * 1024), "v"(hp + 8 * 1024), "v"(hp + 12 * 1024));
    }
    // decode pre(t) from Pcur (value complete; must read BEFORE reissuing Pcur)
    float p0 = bf2f((unsigned short)(Pcur.x & 0xffff));
    float p1 = bf2f((unsigned short)(Pcur.x >> 16));
    float p2 = bf2f((unsigned short)(Pcur.y & 0xffff));
    float p3 = bf2f((unsigned short)(Pcur.y >> 16));
    {
      int tp = (t + 2 < 512) ? (t + 2) : 510;     // clamp: dup load, unused
      const unsigned short* pp = prebase + (size_t)tp * 131072;
      asm volatile("global_load_dwordx2 %0, %1, off" : "=v"(Pcur) : "v"(pp));
    }
    // first-attempt wait: everything older than pre(t+2) retires (h stage
    // loads, pre(t+1), dangling h/flag stores); pre(t+2) stays in flight.
    asm volatile("s_waitcnt vmcnt(1)");
    asm volatile("" : "+v"(Pnxt));        // order next body's decode after wait
    if (notown) {
      // pin each staged vector after the wait (ext_vector_type ties compile)
      asm volatile("" : "+v"(r0));
      asm volatile("" : "+v"(r1));
      asm volatile("" : "+v"(r2));
      asm volatile("" : "+v"(r3));
      i32x4 d0, d1, d2, d3;
      for (;;) {
        // decode == check: XOR by expected tag; any bit14 left set => stale
        d0 = r0 ^ (int)et;
        d1 = r1 ^ (int)et;
        d2 = r2 ^ (int)et;
        d3 = r3 ^ (int)et;
        i32x4 o = d0 | d1 | d2 | d3;
        unsigned int bad = (unsigned int)(o.x | o.y | o.z | o.w) & 0x40004000u;
        if (bad == 0) break;
        // retry (rare): reload + full drain (also retires pre(t+2), harmless)
        asm volatile(
          "global_load_dwordx4 %0, %4, off sc1\n\t"
          "global_load_dwordx4 %1, %5, off sc1\n\t"
          "global_load_dwordx4 %2, %6, off sc1\n\t"
          "global_load_dwordx4 %3, %7, off sc1\n\t"
          "s_waitcnt vmcnt(0)"
          : "=&v"(r0), "=&v"(r1), "=&v"(r2), "=&v"(r3)
          : "v"(hp), "v"(hp + 4 * 1024), "v"(hp + 8 * 1024), "v"(hp + 12 * 1024));
      }
      *(i32x4*)&hlds[sb][sk]      = d0;
      *(i32x4*)&hlds[sb + 4][sk]  = d1;
      *(i32x4*)&hlds[sb + 8][sk]  = d2;
      *(i32x4*)&hlds[sb + 12][sk] = d3;
    }
    *(uint2*)&hlds[l15][i0] = pk;         // own slice from regs (raw, t=0: zeros)
    __syncthreads();   // hlds fully staged (barrier b)

    f32x4 acc0 = {0.f, 0.f, 0.f, 0.f}, acc1 = {0.f, 0.f, 0.f, 0.f};
    #pragma unroll
    for (int kt = 0; kt < 32; kt += 2) {
      short8 b0 = *(const short8*)&hlds[l15][kt * 32 + q * 8];
      short8 b1 = *(const short8*)&hlds[l15][kt * 32 + 32 + q * 8];
      acc0 = __builtin_amdgcn_mfma_f32_16x16x32_bf16(A[kt],     b0, acc0, 0, 0, 0);
      acc1 = __builtin_amdgcn_mfma_f32_16x16x32_bf16(A[kt + 1], b1, acc1, 0, 0, 0);
    }

    // epilogue: D col=lane&15 -> batch, row=4q+r -> i
    float x0 = acc0[0] + acc1[0] + p0 + bias.x;
    float x1 = acc0[1] + acc1[1] + p1 + bias.y;
    float x2 = acc0[2] + acc1[2] + p2 + bias.z;
    float x3 = acc0[3] + acc1[3] + p3 + bias.w;
    pk.x = pack2(fast_tanh(x0), fast_tanh(x1));
    pk.y = pack2(fast_tanh(x2), fast_tanh(x3));
    {
      uint2 pkt; pkt.x = pk.x ^ tm; pkt.y = pk.y ^ tm;
      unsigned short* dst = hnew + (size_t)(bglob + l15) * 1024 + i0;
      asm volatile("global_store_dwordx2 %0, %1, off sc1"
                   : : "v"(dst), "v"(pkt));   // no drain: tags self-validate;
                                              // retired by next stage's vmcnt(1)
    }
    __syncthreads();   // all waves issued h stores + finished hlds reads (barrier d)
    if (tid == 0) {
      unsigned int tv = (unsigned int)(t + 1);
      asm volatile("global_store_dword %0, %1, off sc1" : : "v"(fmine), "v"(tv));
    }
  };

  #pragma unroll 1
  for (int t = 0; t < 512; t += 2) {
    body(t,     P0, P1);
    body(t + 1, P1, P0);
  }
}

// ---------------- final: sigmoid(h_T @ V^T + Vb) ----------------
__global__ __launch_bounds__(64) void final_out(const unsigned short* __restrict__ hT,
                                                const float* __restrict__ Vw,
                                                const float* __restrict__ Vb,
                                                float* __restrict__ out) {
  int b = blockIdx.x, lane = threadIdx.x;
  float sum = 0.f;
  #pragma unroll
  for (int k = 0; k < 16; ++k) {
    int i = k * 64 + lane;
    sum += bf2f(hT[b * 1024 + i]) * Vw[i];
  }
  #pragma unroll
  for (int off = 32; off; off >>= 1) sum += __shfl_down(sum, off);
  if (lane == 0) out[b] = 1.f / (1.f + expf(-(sum + Vb[0])));
}

extern "C" void kernel_launch(void* const* d_in, const int* in_sizes, int n_in,
                              void* d_out, int out_size, void* d_ws, size_t ws_size,
                              hipStream_t stream) {
  const int*   x   = (const int*)d_in[0];
  const float* emb = (const float*)d_in[1];
  const float* W_w = (const float*)d_in[2];
  const float* W_b = (const float*)d_in[3];
  const float* U_w = (const float*)d_in[4];
  const float* U_b = (const float*)d_in[5];
  const float* V_w = (const float*)d_in[6];
  const float* V_b = (const float*)d_in[7];
  float* out = (float*)d_out;
  char*  ws  = (char*)d_ws;

  unsigned short* Ubf = (unsigned short*)(ws + OFF_U);
  unsigned short* Wbf = (unsigned short*)(ws + OFF_W);
  unsigned short* pre = (unsigned short*)(ws + OFF_PRE);
  unsigned short* h0  = (unsigned short*)(ws + OFF_H0);
  unsigned short* h1  = (unsigned short*)(ws + OFF_H1);
  unsigned int*   cnt = (unsigned int*)(ws + OFF_CNT);

  // zero h0 (h_{-1}, tag 0 == valid zeros) + h1 + flags. Re-runs every replay.
  hipMemsetAsync(ws + OFF_H0, 0, (OFF_CNT - OFF_H0) + 0x1000, stream);

  cvt_bf16<<<1024, 256, 0, stream>>>(U_w, Ubf, 1024 * 1024 / 4);
  cvt_bf16<<<512, 256, 0, stream>>>(W_w, Wbf, 1024 * 512 / 4);

  pre_gemm<<<dim3(8, 512), 256, 0, stream>>>(x, emb, Wbf, pre);

  void* args[] = {&Ubf, &pre, &W_b, &U_b, &h0, &h1, &cnt};
  hipLaunchCooperativeKernel((void*)recurrence, dim3(64), dim3(512), args, 0, stream);

  // t=511 writes h0 with tag(511)=0 (raw bf16)
  final_out<<<128, 64, 0, stream>>>(h0, V_w, V_b, out);
}